// Round 1
// baseline (507.571 us; speedup 1.0000x reference)
//
#include <hip/hip_runtime.h>

// EdgeFormerINT4Linear: y[b,s,o] = sum_i x[b,s,i] * q[o,i] * scale[o] + bias[o]
// M=8192 (4*2048), K=4096, N=4096.
// Strategy: convert x -> bf16 (A), q -> bf16 exact (B, unscaled), bf16 MFMA GEMM
// with scale/bias fused in fp32 epilogue. m97-style 128x128 tile, BK=64,
// global_load_lds width-16 staging, XOR-swizzled LDS chunk layout.

#define M_ROWS 8192
#define N_COLS 4096
#define K_DIM  4096

typedef __bf16 bf16;
typedef bf16 bf16x8 __attribute__((ext_vector_type(8)));
typedef float f32x4 __attribute__((ext_vector_type(4)));

__device__ __forceinline__ void async16(const void* g, void* l) {
  __builtin_amdgcn_global_load_lds(
      (const __attribute__((address_space(1))) void*)g,
      (__attribute__((address_space(3))) void*)l,
      16 /*bytes*/, 0 /*offset*/, 0 /*aux*/);
}

// ---- pre-pass: x fp32 -> bf16 (8 elems/thread) ----
__global__ __launch_bounds__(256) void cvt_x_kernel(const float4* __restrict__ in,
                                                    bf16x8* __restrict__ out) {
  const int i = blockIdx.x * 256 + threadIdx.x;
  float4 a = in[2 * i];
  float4 b = in[2 * i + 1];
  bf16x8 o;
  o[0] = (bf16)a.x; o[1] = (bf16)a.y; o[2] = (bf16)a.z; o[3] = (bf16)a.w;
  o[4] = (bf16)b.x; o[5] = (bf16)b.y; o[6] = (bf16)b.z; o[7] = (bf16)b.w;
  out[i] = o;
}

// ---- pre-pass: q int32 (-8..7) -> bf16 exact (8 elems/thread) ----
__global__ __launch_bounds__(256) void cvt_q_kernel(const int4* __restrict__ in,
                                                    bf16x8* __restrict__ out) {
  const int i = blockIdx.x * 256 + threadIdx.x;
  int4 a = in[2 * i];
  int4 b = in[2 * i + 1];
  bf16x8 o;
  o[0] = (bf16)(float)a.x; o[1] = (bf16)(float)a.y;
  o[2] = (bf16)(float)a.z; o[3] = (bf16)(float)a.w;
  o[4] = (bf16)(float)b.x; o[5] = (bf16)(float)b.y;
  o[6] = (bf16)(float)b.z; o[7] = (bf16)(float)b.w;
  out[i] = o;
}

// ---- GEMM: A[M,K] bf16 row-major, B[N,K] bf16 row-major (B^T form) ----
// Block = 256 threads (4 waves), tile 128x128, BK=64.
// Wave w: wr=w>>1 (row half), wc=w&1 (col half); each wave does 64x64 = 4x4
// grid of 16x16x32 MFMAs.
// LDS tile layout: 1024 chunks of 16B, chunk ch=(r,cc) holds global chunk
// (r, cc ^ (r&7)) -> fragment reads hit all 32 banks (2-way only = free).
__global__ __launch_bounds__(256, 3) void gemm_kernel(
    const bf16* __restrict__ A, const bf16* __restrict__ B,
    const float* __restrict__ scale, const float* __restrict__ bias,
    float* __restrict__ out) {
  __shared__ __attribute__((aligned(16))) bf16 sA[128 * 64];
  __shared__ __attribute__((aligned(16))) bf16 sB[128 * 64];

  const int tid  = threadIdx.x;
  const int lane = tid & 63;
  const int w    = tid >> 6;
  const int wr   = w >> 1;
  const int wc   = w & 1;
  const int lm   = lane & 15;   // m (A) / n (B) / col (C) index within 16
  const int lk   = lane >> 4;   // k-group 0..3

  const int m0 = blockIdx.y * 128;
  const int n0 = blockIdx.x * 128;

  f32x4 acc[4][4];
#pragma unroll
  for (int i = 0; i < 4; ++i)
#pragma unroll
    for (int j = 0; j < 4; ++j)
      acc[i][j] = (f32x4){0.f, 0.f, 0.f, 0.f};

  for (int it = 0; it < K_DIM / 64; ++it) {
    const int k0 = it * 64;
    // stage A and B tiles: 4 rounds x 256 threads x 16B each = 16 KB per tile
#pragma unroll
    for (int i = 0; i < 4; ++i) {
      const int ch = i * 256 + tid;          // chunk index 0..1023
      const int r  = ch >> 3;                // tile row 0..127
      const int sc = (ch & 7) ^ (r & 7);     // swizzled source col-chunk
      async16(A + (size_t)(m0 + r) * K_DIM + k0 + sc * 8, (char*)sA + ch * 16);
      async16(B + (size_t)(n0 + r) * K_DIM + k0 + sc * 8, (char*)sB + ch * 16);
    }
    __syncthreads();   // compiler emits vmcnt(0) drain before barrier

#pragma unroll
    for (int ks = 0; ks < 2; ++ks) {
      bf16x8 af[4], bfr[4];
      const int kc = ks * 4 + lk;            // k-chunk 0..7 within BK=64
#pragma unroll
      for (int i = 0; i < 4; ++i) {
        const int row = wr * 64 + i * 16 + lm;
        af[i] = *(const bf16x8*)(sA + ((row * 8) + (kc ^ (row & 7))) * 8);
      }
#pragma unroll
      for (int j = 0; j < 4; ++j) {
        const int row = wc * 64 + j * 16 + lm;
        bfr[j] = *(const bf16x8*)(sB + ((row * 8) + (kc ^ (row & 7))) * 8);
      }
#pragma unroll
      for (int i = 0; i < 4; ++i)
#pragma unroll
        for (int j = 0; j < 4; ++j)
          acc[i][j] = __builtin_amdgcn_mfma_f32_16x16x32_bf16(af[i], bfr[j],
                                                              acc[i][j], 0, 0, 0);
    }
    __syncthreads();
  }

  // epilogue: C/D layout col=lane&15 (n), row=(lane>>4)*4+reg (m)
#pragma unroll
  for (int j = 0; j < 4; ++j) {
    const int o   = n0 + wc * 64 + j * 16 + lm;
    const float s = scale[o];
    const float bz = bias[o];
#pragma unroll
    for (int i = 0; i < 4; ++i) {
      const int mbase = m0 + wr * 64 + i * 16 + lk * 4;
#pragma unroll
      for (int r = 0; r < 4; ++r) {
        out[(size_t)(mbase + r) * N_COLS + o] = acc[i][j][r] * s + bz;
      }
    }
  }
}

extern "C" void kernel_launch(void* const* d_in, const int* in_sizes, int n_in,
                              void* d_out, int out_size, void* d_ws, size_t ws_size,
                              hipStream_t stream) {
  const float* x     = (const float*)d_in[0];   // [4,2048,4096] fp32
  const int*   q     = (const int*)d_in[1];     // [4096,4096] int32 in [-8,7]
  const float* scale = (const float*)d_in[2];   // [4096] fp32
  const float* bias  = (const float*)d_in[3];   // [4096] fp32
  float* out = (float*)d_out;                   // [4,2048,4096] fp32

  // workspace: A_bf16 (64 MiB) then B_bf16 (32 MiB)
  bf16* Abf = (bf16*)d_ws;
  bf16* Bbf = (bf16*)((char*)d_ws + (size_t)M_ROWS * K_DIM * sizeof(bf16));

  // x: 33554432 elems / 8 per thread / 256 per block = 16384 blocks
  cvt_x_kernel<<<16384, 256, 0, stream>>>((const float4*)x, (bf16x8*)Abf);
  // q: 16777216 elems / 8 / 256 = 8192 blocks
  cvt_q_kernel<<<8192, 256, 0, stream>>>((const int4*)q, (bf16x8*)Bbf);

  dim3 grid(N_COLS / 128, M_ROWS / 128);  // 32 x 64 = 2048 blocks
  gemm_kernel<<<grid, 256, 0, stream>>>(Abf, Bbf, scale, bias, out);
}

// Round 2
// 389.291 us; speedup vs baseline: 1.3038x; 1.3038x over previous
//
#include <hip/hip_runtime.h>

// EdgeFormerINT4Linear via INT8 dynamic quantization:
// y[m,o] = (sum_i xq[m,i]*q[o,i]) * (srow[m]*scale[o]) + bias[o]
// xq = round(x / srow*127) int8 per-row symmetric; q in [-8,7] exact in int8.
// GEMM: mfma_i32_16x16x64_i8, 128x128 tile, BK=128, global_load_lds width-16,
// XOR-swizzled 16B-chunk LDS layout (verified 0 bank conflicts in round 1).

#define M_ROWS 8192
#define N_COLS 4096
#define K_DIM  4096

typedef int int32x4 __attribute__((ext_vector_type(4)));

__device__ __forceinline__ void async16(const void* g, void* l) {
  __builtin_amdgcn_global_load_lds(
      (const __attribute__((address_space(1))) void*)g,
      (__attribute__((address_space(3))) void*)l,
      16 /*bytes*/, 0 /*offset*/, 0 /*aux*/);
}

// ---- pre-pass 1: per-row symmetric int8 quant of x ----
// One block per row (8192 blocks). 256 threads x 16 elems.
__global__ __launch_bounds__(256) void quant_x_kernel(const float4* __restrict__ x,
                                                      int* __restrict__ xq,
                                                      float* __restrict__ srow) {
  const int row = blockIdx.x;
  const int t   = threadIdx.x;
  const float4* xr = x + (size_t)row * (K_DIM / 4);
  float4 v[4];
  float am = 0.f;
#pragma unroll
  for (int j = 0; j < 4; ++j) {
    v[j] = xr[t + 256 * j];
    am = fmaxf(am, fmaxf(fmaxf(fabsf(v[j].x), fabsf(v[j].y)),
                         fmaxf(fabsf(v[j].z), fabsf(v[j].w))));
  }
#pragma unroll
  for (int off = 32; off > 0; off >>= 1)
    am = fmaxf(am, __shfl_down(am, off, 64));
  __shared__ float wmax[4];
  if ((t & 63) == 0) wmax[t >> 6] = am;
  __syncthreads();
  am = fmaxf(fmaxf(wmax[0], wmax[1]), fmaxf(wmax[2], wmax[3]));
  const float s   = am * (1.f / 127.f);
  const float inv = (am > 0.f) ? 127.f / am : 0.f;
  if (t == 0) srow[row] = s;
  int* o = xq + (size_t)row * (K_DIM / 4);
#pragma unroll
  for (int j = 0; j < 4; ++j) {
    int a = __float2int_rn(v[j].x * inv);
    int b = __float2int_rn(v[j].y * inv);
    int c = __float2int_rn(v[j].z * inv);
    int d = __float2int_rn(v[j].w * inv);
    o[t + 256 * j] = (a & 0xff) | ((b & 0xff) << 8) | ((c & 0xff) << 16) | (d << 24);
  }
}

// ---- pre-pass 2: q int32 -> int8 pack (4 elems/thread) ----
__global__ __launch_bounds__(256) void cvt_q8_kernel(const int4* __restrict__ q,
                                                     int* __restrict__ q8) {
  const int i = blockIdx.x * 256 + threadIdx.x;
  int4 v = q[i];
  q8[i] = (v.x & 0xff) | ((v.y & 0xff) << 8) | ((v.z & 0xff) << 16) | (v.w << 24);
}

// ---- GEMM: A[M,K] int8 row-major, B[N,K] int8 row-major (B^T form) ----
// Block = 256 threads (4 waves), tile 128x128, BK=128 (128 B per tile row =
// 8 chunks of 16B -> identical chunk geometry/swizzle to the verified bf16
// version). Each wave: 4x4 grid of 16x16x64 i8 MFMAs, 2 per K-sub-step.
__global__ __launch_bounds__(256, 4) void gemm_i8_kernel(
    const char* __restrict__ A, const char* __restrict__ B,
    const float* __restrict__ scale, const float* __restrict__ srow,
    const float* __restrict__ bias, float* __restrict__ out) {
  __shared__ __attribute__((aligned(16))) char sA[128 * 128];
  __shared__ __attribute__((aligned(16))) char sB[128 * 128];

  const int tid  = threadIdx.x;
  const int lane = tid & 63;
  const int w    = tid >> 6;
  const int wr   = w >> 1;
  const int wc   = w & 1;
  const int lm   = lane & 15;   // m (A) / n (B) / col (C)
  const int lk   = lane >> 4;   // k-group 0..3

  const int m0 = blockIdx.y * 128;
  const int n0 = blockIdx.x * 128;

  int32x4 acc[4][4];
#pragma unroll
  for (int i = 0; i < 4; ++i)
#pragma unroll
    for (int j = 0; j < 4; ++j)
      acc[i][j] = (int32x4){0, 0, 0, 0};

  for (int it = 0; it < K_DIM / 128; ++it) {
    const int k0 = it * 128;   // byte offset within a row (1 int8 = 1 byte)
#pragma unroll
    for (int i = 0; i < 4; ++i) {
      const int ch = i * 256 + tid;          // chunk 0..1023
      const int r  = ch >> 3;                // tile row 0..127
      const int sc = (ch & 7) ^ (r & 7);     // swizzled source col-chunk
      async16(A + (size_t)(m0 + r) * K_DIM + k0 + sc * 16, sA + ch * 16);
      async16(B + (size_t)(n0 + r) * K_DIM + k0 + sc * 16, sB + ch * 16);
    }
    __syncthreads();

#pragma unroll
    for (int ks = 0; ks < 2; ++ks) {
      int32x4 af[4], bfr[4];
      const int kc = ks * 4 + lk;            // 16B-chunk 0..7 within BK=128
#pragma unroll
      for (int i = 0; i < 4; ++i) {
        const int row = wr * 64 + i * 16 + lm;
        af[i] = *(const int32x4*)(sA + ((row * 8) + (kc ^ (row & 7))) * 16);
      }
#pragma unroll
      for (int j = 0; j < 4; ++j) {
        const int row = wc * 64 + j * 16 + lm;
        bfr[j] = *(const int32x4*)(sB + ((row * 8) + (kc ^ (row & 7))) * 16);
      }
#pragma unroll
      for (int i = 0; i < 4; ++i)
#pragma unroll
        for (int j = 0; j < 4; ++j)
          acc[i][j] = __builtin_amdgcn_mfma_i32_16x16x64_i8(af[i], bfr[j],
                                                            acc[i][j], 0, 0, 0);
    }
    __syncthreads();
  }

  // epilogue: C/D layout col=lane&15 (n), row=(lane>>4)*4+reg (m)
#pragma unroll
  for (int j = 0; j < 4; ++j) {
    const int o    = n0 + wc * 64 + j * 16 + lm;
    const float so = scale[o];
    const float bz = bias[o];
#pragma unroll
    for (int i = 0; i < 4; ++i) {
      const int mbase = m0 + wr * 64 + i * 16 + lk * 4;
#pragma unroll
      for (int r = 0; r < 4; ++r) {
        const int m = mbase + r;
        out[(size_t)m * N_COLS + o] = (float)acc[i][j][r] * (so * srow[m]) + bz;
      }
    }
  }
}

extern "C" void kernel_launch(void* const* d_in, const int* in_sizes, int n_in,
                              void* d_out, int out_size, void* d_ws, size_t ws_size,
                              hipStream_t stream) {
  const float* x     = (const float*)d_in[0];   // [4,2048,4096] fp32
  const int*   q     = (const int*)d_in[1];     // [4096,4096] int32 in [-8,7]
  const float* scale = (const float*)d_in[2];   // [4096]
  const float* bias  = (const float*)d_in[3];   // [4096]
  float* out = (float*)d_out;                   // [8192,4096] fp32

  // workspace: A8 (32 MiB) | B8 (16 MiB) | srow (32 KiB)
  char*  A8   = (char*)d_ws;
  char*  B8   = (char*)d_ws + (size_t)M_ROWS * K_DIM;
  float* srow = (float*)((char*)B8 + (size_t)N_COLS * K_DIM);

  quant_x_kernel<<<M_ROWS, 256, 0, stream>>>((const float4*)x, (int*)A8, srow);
  cvt_q8_kernel<<<(N_COLS * K_DIM / 4) / 256, 256, 0, stream>>>((const int4*)q,
                                                                (int*)B8);
  dim3 grid(N_COLS / 128, M_ROWS / 128);  // 32 x 64 = 2048 blocks
  gemm_i8_kernel<<<grid, 256, 0, stream>>>(A8, B8, scale, srow, bias, out);
}